// Round 1
// baseline (100.941 us; speedup 1.0000x reference)
//
#include <hip/hip_runtime.h>
#include <cstddef>

static constexpr int B = 64, T = 64, V = 64, C = 65;

// logaddexp matching jnp: m + log1p(exp(-|x-y|))
__device__ __forceinline__ float logaddexp_f(float x, float y) {
    float m = fmaxf(x, y);
    return m + log1pf(__expf(-fabsf(x - y)));
}

// Phase 1: gather dsc/isc/ssc (each [B,T,V]) from action_scores [B,T,V,C].
// One block per (b,t) row, lane = v. Wide grid -> full-chip scattered-read BW.
__global__ void gather_kernel(const float* __restrict__ as,
                              const int* __restrict__ del_ids,   // [B,T]
                              const int* __restrict__ ins_ids,   // [B,V]
                              const int* __restrict__ sub_ids,   // [B,T,V]
                              float* __restrict__ dsc,
                              float* __restrict__ isc,
                              float* __restrict__ ssc) {
    const int bt = blockIdx.x;        // b*T + t
    const int b  = bt >> 6;
    const int v  = threadIdx.x;
    const int del_id = del_ids[bt];            // wave-uniform (scalar load)
    const int ins_id = ins_ids[b * V + v];     // coalesced
    const int sub_id = sub_ids[bt * V + v];    // coalesced
    const size_t row = ((size_t)bt * V + v) * C;
    const float dval = as[row + del_id];
    const float ival = as[row + ins_id];
    const float sval = as[row + sub_id];
    const int o = bt * V + v;
    dsc[o] = dval;
    isc[o] = ival;
    ssc[o] = sval;
}

// Phase 2: anti-diagonal wavefront DP. One block = one wave = one batch b.
// Lane v owns column v; at diagonal step d it computes alpha[t=d-v, v].
// Left-neighbor deps come via __shfl_up of the neighbor's last two alphas.
template <bool GATHERED>
__global__ void __launch_bounds__(V) dp_kernel(
    const float* __restrict__ as,
    const int* __restrict__ del_ids,
    const int* __restrict__ ins_ids,
    const int* __restrict__ sub_ids,
    const float* __restrict__ dscg,
    const float* __restrict__ iscg,
    const float* __restrict__ sscg,
    float* __restrict__ out) {
    __shared__ float s_dsc[T][V];   // dsc; each cell is overwritten by alpha once consumed
    __shared__ float s_isc[T][V];
    __shared__ float s_ssc[T][V];

    const int b = blockIdx.x;
    const int v = threadIdx.x;

    if (GATHERED) {
        #pragma unroll 4
        for (int t = 0; t < T; ++t) {
            const int o = (b * T + t) * V + v;
            s_dsc[t][v] = dscg[o];
            s_isc[t][v] = iscg[o];
            s_ssc[t][v] = sscg[o];
        }
    } else {
        const int ins_id = ins_ids[b * V + v];
        for (int t = 0; t < T; ++t) {
            const int bt = b * T + t;
            const int del_id = del_ids[bt];
            const int sub_id = sub_ids[bt * V + v];
            const size_t row = ((size_t)bt * V + v) * C;
            s_dsc[t][v] = as[row + del_id];
            s_isc[t][v] = as[row + ins_id];
            s_ssc[t][v] = as[row + sub_id];
        }
    }
    __syncthreads();

    float a1 = 0.0f;  // alpha[t-1, v]   (own value from previous diagonal)
    float a2 = 0.0f;  // alpha[t-2, v]   (two diagonals back)
    for (int d = 0; d < T + V - 1; ++d) {
        const float lf1 = __shfl_up(a1, 1);  // alpha[t,   v-1]
        const float lf2 = __shfl_up(a2, 1);  // alpha[t-1, v-1]
        const int t = d - v;
        const bool active = (t >= 0) && (t < T);
        const int tc = t < 0 ? 0 : (t > T - 1 ? T - 1 : t);
        const float dv = s_dsc[tc][v];
        const float iv = s_isc[tc][v];
        const float sv = s_ssc[tc][v];
        float a;
        if (t <= 0) {
            // row 0: cumsum of insertions, alpha[0,0] = 0
            a = (v == 0) ? 0.0f : (iv + lf1);
        } else if (v == 0) {
            // col 0: deletions only
            a = dv + a1;
        } else {
            // reference association order: LSE(LSE(d+up, s+diag), i+left)
            const float base = logaddexp_f(dv + a1, sv + lf2);
            a = logaddexp_f(base, iv + lf1);
        }
        if (active) {
            s_dsc[tc][v] = a;   // dsc[tc][v] is dead; store alpha in its slot
            a2 = a1;
            a1 = a;
        }
    }
    __syncthreads();

    #pragma unroll 4
    for (int t = 0; t < T; ++t) {
        out[(b * T + t) * V + v] = s_dsc[t][v];   // coalesced f32 store
    }
}

extern "C" void kernel_launch(void* const* d_in, const int* in_sizes, int n_in,
                              void* d_out, int out_size, void* d_ws, size_t ws_size,
                              hipStream_t stream) {
    const float* as      = (const float*)d_in[0];
    const int*   del_ids = (const int*)d_in[1];
    const int*   ins_ids = (const int*)d_in[2];
    const int*   sub_ids = (const int*)d_in[3];
    float*       out     = (float*)d_out;

    const size_t need = (size_t)3 * B * T * V * sizeof(float);
    if (ws_size >= need) {
        float* dsc = (float*)d_ws;
        float* isc = dsc + (size_t)B * T * V;
        float* ssc = isc + (size_t)B * T * V;
        gather_kernel<<<B * T, V, 0, stream>>>(as, del_ids, ins_ids, sub_ids, dsc, isc, ssc);
        dp_kernel<true><<<B, V, 0, stream>>>(as, del_ids, ins_ids, sub_ids, dsc, isc, ssc, out);
    } else {
        dp_kernel<false><<<B, V, 0, stream>>>(as, del_ids, ins_ids, sub_ids,
                                              nullptr, nullptr, nullptr, out);
    }
}

// Round 2
// 41.502 us; speedup vs baseline: 2.4322x; 2.4322x over previous
//
#include <hip/hip_runtime.h>
#include <cstddef>

static constexpr int B = 64, T = 64, V = 64, C = 65;
static constexpr float NEG = -1.0e30f;   // log-space "zero" sentinel

// Fast logaddexp via HW exp2/log2. For y <= x - 88: returns x EXACTLY
// (__expf underflows to 0, __logf(1) == 0). Matches jnp.logaddexp to ~1e-6.
__device__ __forceinline__ float lse(float x, float y) {
    const float m = fmaxf(x, y);
    const float e = __expf(-fabsf(x - y));
    return m + __logf(1.0f + e);
}

// Phase 1: gather dsc/isc/ssc (each [B,T,V]) from action_scores [B,T,V,C].
// One block per (b,t) row, lane = v. Wide grid -> full-chip scattered-read BW.
__global__ void gather_kernel(const float* __restrict__ as,
                              const int* __restrict__ del_ids,   // [B,T]
                              const int* __restrict__ ins_ids,   // [B,V]
                              const int* __restrict__ sub_ids,   // [B,T,V]
                              float* __restrict__ dsc,
                              float* __restrict__ isc,
                              float* __restrict__ ssc) {
    const int bt = blockIdx.x;        // b*T + t
    const int b  = bt >> 6;
    const int v  = threadIdx.x;
    const int del_id = del_ids[bt];            // wave-uniform
    const int ins_id = ins_ids[b * V + v];     // coalesced
    const int sub_id = sub_ids[bt * V + v];    // coalesced
    const size_t row = ((size_t)bt * V + v) * C;
    const float dval = as[row + del_id];
    const float ival = as[row + ins_id];
    const float sval = as[row + sub_id];
    const int o = bt * V + v;
    dsc[o] = dval;
    isc[o] = ival;
    ssc[o] = sval;
}

// Phase 2: anti-diagonal wavefront DP. One block = one wave = one batch b.
// Lane v owns column v; at diagonal step d it computes alpha[t=d-v, v].
// Branchless: alpha[-1][*] = NEG sentinel; lse() returns the finite arg
// exactly when the other is ~NEG, so row-0 cumsum / col-0 chain are exact.
template <bool GATHERED>
__global__ void __launch_bounds__(V) dp_kernel(
    const float* __restrict__ as,
    const int* __restrict__ del_ids,
    const int* __restrict__ ins_ids,
    const int* __restrict__ sub_ids,
    const float* __restrict__ dscg,
    const float* __restrict__ iscg,
    const float* __restrict__ sscg,
    float* __restrict__ out) {
    __shared__ float s_d[T][V];
    __shared__ float s_i[T][V];
    __shared__ float s_s[T][V];
    __shared__ float s_a[T][V];   // alpha output — separate array: no RW alias,
                                  // score reads stay freely prefetchable

    const int b = blockIdx.x;
    const int v = threadIdx.x;

    if (GATHERED) {
        #pragma unroll 8
        for (int t = 0; t < T; ++t) {
            const int o = (b * T + t) * V + v;
            s_d[t][v] = dscg[o];
            s_i[t][v] = iscg[o];
            s_s[t][v] = sscg[o];
        }
    } else {
        const int ins_id = ins_ids[b * V + v];
        for (int t = 0; t < T; ++t) {
            const int bt = b * T + t;
            const int del_id = del_ids[bt];
            const int sub_id = sub_ids[bt * V + v];
            const size_t row = ((size_t)bt * V + v) * C;
            s_d[t][v] = as[row + del_id];
            s_i[t][v] = as[row + ins_id];
            s_s[t][v] = as[row + sub_id];
        }
    }
    __syncthreads();

    // State as-if diagonal d=0 is done: alpha[0][0] = 0, others pre-activation.
    float a1 = (v == 0) ? 0.0f : NEG;  // alpha[d-1 - v][v]  (own, prev diag)
    float a2 = NEG;                    // alpha[d-2 - v][v]
    if (v == 0) s_a[0][0] = 0.0f;
    const bool lane0 = (v == 0);

    #pragma unroll 3
    for (int d = 1; d < T + V - 1; ++d) {
        float lf1 = __shfl_up(a1, 1);  // alpha[t,   v-1]
        float lf2 = __shfl_up(a2, 1);  // alpha[t-1, v-1]
        if (lane0) { lf1 = NEG; lf2 = NEG; }
        const int t  = d - v;
        const int tc = min(max(t, 0), T - 1);
        const float dv = s_d[tc][v];
        const float iv = s_i[tc][v];
        const float sv = s_s[tc][v];
        // base overlaps the shuffle latency (only needs lane-local a1 / lf2).
        const float base = lse(dv + a1, sv + lf2);
        const float a    = lse(base, iv + lf1);
        if (t >= 0 && t < T) s_a[t][v] = a;   // masked ds_write, off-chain
        a2 = a1;
        a1 = a;
    }
    __syncthreads();

    #pragma unroll 8
    for (int t = 0; t < T; ++t) {
        out[(b * T + t) * V + v] = s_a[t][v];   // coalesced f32 store
    }
}

extern "C" void kernel_launch(void* const* d_in, const int* in_sizes, int n_in,
                              void* d_out, int out_size, void* d_ws, size_t ws_size,
                              hipStream_t stream) {
    const float* as      = (const float*)d_in[0];
    const int*   del_ids = (const int*)d_in[1];
    const int*   ins_ids = (const int*)d_in[2];
    const int*   sub_ids = (const int*)d_in[3];
    float*       out     = (float*)d_out;

    const size_t need = (size_t)3 * B * T * V * sizeof(float);
    if (ws_size >= need) {
        float* dsc = (float*)d_ws;
        float* isc = dsc + (size_t)B * T * V;
        float* ssc = isc + (size_t)B * T * V;
        gather_kernel<<<B * T, V, 0, stream>>>(as, del_ids, ins_ids, sub_ids, dsc, isc, ssc);
        dp_kernel<true><<<B, V, 0, stream>>>(as, del_ids, ins_ids, sub_ids, dsc, isc, ssc, out);
    } else {
        dp_kernel<false><<<B, V, 0, stream>>>(as, del_ids, ins_ids, sub_ids,
                                              nullptr, nullptr, nullptr, out);
    }
}

// Round 3
// 33.909 us; speedup vs baseline: 2.9768x; 1.2239x over previous
//
#include <hip/hip_runtime.h>
#include <cstddef>

static constexpr int B = 64, T = 64, V = 64, C = 65;
static constexpr float NEG = -1.0e30f;   // log-space "zero" sentinel

// lane i gets lane i-1's value; lane 0 keeps its own (we override with NEG).
// DPP wave_shr:1 (ctrl 0x138) — pure VALU, no DS pipe, ~4 cy.
__device__ __forceinline__ float wave_shr1(float x) {
    int xi = __float_as_int(x);
    int r = __builtin_amdgcn_update_dpp(xi, xi, 0x138, 0xf, 0xf, false);
    return __int_as_float(r);
}

// 3-way logaddexp: m + log(sum exp(xi-m)). One transcendental chain instead
// of two nested lse(). Exact for NEG-sentinel args (exp underflows to 0).
__device__ __forceinline__ float lse3(float x, float y, float z) {
    const float m = fmaxf(fmaxf(x, y), z);   // clang fuses to v_max3_f32
    const float s = __expf(x - m) + __expf(y - m) + __expf(z - m);
    return m + __logf(s);
}

// Phase 1: one block per (b,t). Stage the contiguous 64x65-float row block
// (16640 B) into LDS with coalesced float4 streams, then 192 lanes do the
// random picks from LDS. Converts 64-way-scattered dword loads into
// full-BW streaming reads.
__global__ void __launch_bounds__(256) gather_kernel(
    const float* __restrict__ as,
    const int* __restrict__ del_ids,   // [B,T]
    const int* __restrict__ ins_ids,   // [B,V]
    const int* __restrict__ sub_ids,   // [B,T,V]
    float* __restrict__ dsc,
    float* __restrict__ isc,
    float* __restrict__ ssc) {
    __shared__ float4 s4[1040];        // 64 rows x 65 floats = 4160 f = 1040 f4
    const int bt  = blockIdx.x;        // b*T + t
    const int tid = threadIdx.x;
    const float4* __restrict__ src4 =
        (const float4*)(as + (size_t)bt * (V * C));
    #pragma unroll
    for (int i = 0; i < 4; ++i) {
        const int idx = tid + i * 256;   // 0..1023
        s4[idx] = src4[idx];
    }
    if (tid < 16) s4[1024 + tid] = src4[1024 + tid];
    __syncthreads();

    const float* __restrict__ s = (const float*)s4;
    const int b = bt >> 6;
    const int v = tid & 63;
    const int o = bt * V + v;
    if (tid < 64) {
        dsc[o] = s[v * C + del_ids[bt]];
    } else if (tid < 128) {
        isc[o] = s[v * C + ins_ids[b * V + v]];
    } else if (tid < 192) {
        ssc[o] = s[v * C + sub_ids[o]];
    }
}

// Phase 2: anti-diagonal wavefront DP. One block = one wave = one batch b.
// Lane v owns column v; at diagonal step d it computes alpha[t=d-v, v].
// Branchless sentinel scheme: all inactive lanes carry ~NEG, which lse3
// passes through exactly; only alpha[0][0]=0 is peeled.
__global__ void __launch_bounds__(V) dp_kernel(
    const float* __restrict__ dscg,
    const float* __restrict__ iscg,
    const float* __restrict__ sscg,
    float* __restrict__ out) {
    __shared__ float smem[4][T * V];   // [0]=d [1]=i [2]=s [3]=alpha
    const int b = blockIdx.x;
    const int v = threadIdx.x;

    // Vectorized load: each instruction reads 4 rows x 64 f = 1024 B coalesced.
    {
        const int tq = v >> 4;           // 0..3
        const int cq = (v & 15) * 4;     // 0,4,...,60
        #pragma unroll
        for (int t4 = 0; t4 < T; t4 += 4) {
            const int t = t4 + tq;
            const int go = (b * T + t) * V + cq;
            const int so = t * V + cq;
            *(float4*)&smem[0][so] = *(const float4*)&dscg[go];
            *(float4*)&smem[1][so] = *(const float4*)&iscg[go];
            *(float4*)&smem[2][so] = *(const float4*)&sscg[go];
        }
    }
    __syncthreads();

    // State as-if diagonal d=0 done: alpha[0][0]=0, everything else ~NEG.
    float a1 = (v == 0) ? 0.0f : NEG;  // own value, previous diagonal
    float a2 = NEG;                    // own value, two diagonals back
    if (v == 0) smem[3][0] = 0.0f;
    const bool lane0 = (v == 0);

    #pragma unroll 6
    for (int d = 1; d < T + V - 1; ++d) {
        float lf1 = wave_shr1(a1);     // alpha[t,   v-1]
        float lf2 = wave_shr1(a2);     // alpha[t-1, v-1]
        if (lane0) { lf1 = NEG; lf2 = NEG; }
        const int t   = d - v;
        const int tc  = min(max(t, 0), T - 1);
        const int off = tc * V + v;    // one addr reg; 3 ds_reads via imm offset
        const float dv = smem[0][off];
        const float iv = smem[1][off];
        const float sv = smem[2][off];
        const float a  = lse3(dv + a1, sv + lf2, iv + lf1);
        if (t >= 0 && t < T) smem[3][t * V + v] = a;   // off-chain ds_write
        a2 = a1;
        a1 = a;
    }
    __syncthreads();

    // Coalesced vectorized store of alpha.
    {
        const int tq = v >> 4;
        const int cq = (v & 15) * 4;
        #pragma unroll
        for (int t4 = 0; t4 < T; t4 += 4) {
            const int t = t4 + tq;
            *(float4*)&out[(b * T + t) * V + cq] = *(const float4*)&smem[3][t * V + cq];
        }
    }
}

extern "C" void kernel_launch(void* const* d_in, const int* in_sizes, int n_in,
                              void* d_out, int out_size, void* d_ws, size_t ws_size,
                              hipStream_t stream) {
    const float* as      = (const float*)d_in[0];
    const int*   del_ids = (const int*)d_in[1];
    const int*   ins_ids = (const int*)d_in[2];
    const int*   sub_ids = (const int*)d_in[3];
    float*       out     = (float*)d_out;

    float* dsc = (float*)d_ws;
    float* isc = dsc + (size_t)B * T * V;
    float* ssc = isc + (size_t)B * T * V;
    gather_kernel<<<B * T, 256, 0, stream>>>(as, del_ids, ins_ids, sub_ids, dsc, isc, ssc);
    dp_kernel<<<B, V, 0, stream>>>(dsc, isc, ssc, out);
}

// Round 4
// 24.636 us; speedup vs baseline: 4.0973x; 1.3764x over previous
//
#include <hip/hip_runtime.h>
#include <cstddef>

static constexpr int B = 64, T = 64, V = 64, C = 65;
static constexpr float NEG   = -1.0e30f;                  // log-space "zero"
static constexpr float LOG2E = 1.44269504088896340736f;
static constexpr float LN2   = 0.69314718055994530942f;

// Raw HW transcendentals: v_exp_f32 = 2^x, v_log_f32 = log2(x).
__device__ __forceinline__ float fexp2(float x) {
    float r; asm("v_exp_f32 %0, %1" : "=v"(r) : "v"(x)); return r;
}
__device__ __forceinline__ float flog2(float x) {
    float r; asm("v_log_f32 %0, %1" : "=v"(r) : "v"(x)); return r;
}

// lane i <- lane i-1; lane 0 <- `old` (= NEG sentinel). Pure-VALU DPP,
// the NEG boundary folds into the shuffle (no cndmask on the chain).
__device__ __forceinline__ float shr1(float x, int negi) {
    return __int_as_float(__builtin_amdgcn_update_dpp(
        negi, __float_as_int(x), 0x138 /*wave_shr:1*/, 0xf, 0xf, false));
}

// Gather: one block per (b,t) row-block, 3 waves = {del, ins, sub} picks.
// Scattered dword loads touch only the ~2.8 needed 64B lines per 260B row
// (~47 MB total vs 68 MB streamed). Scores pre-scaled by log2e so the DP
// chain runs in pure exp2/log2 domain. Output packed g[b][3][t][v] so the
// DP kernel stages one contiguous 48 KB block.
__global__ void __launch_bounds__(192) gather_kernel(
    const float* __restrict__ as,
    const int* __restrict__ del_ids,   // [B,T]
    const int* __restrict__ ins_ids,   // [B,V]
    const int* __restrict__ sub_ids,   // [B,T,V]
    float* __restrict__ g)             // [B][3][T*V]
{
    const int bt = blockIdx.x, b = bt >> 6, t = bt & 63;
    const int tid = threadIdx.x, v = tid & 63, kind = tid >> 6; // wave-uniform
    int id;
    if (kind == 0)      id = del_ids[bt];
    else if (kind == 1) id = ins_ids[b * V + v];
    else                id = sub_ids[bt * V + v];
    const float val = as[(size_t)(bt * V + v) * C + id] * LOG2E;
    g[((b * 3 + kind) * T + t) * V + v] = val;
}

// DP: one block per batch; wave 0 runs the 126-step anti-diagonal chain,
// all 4 waves stage/store. Alpha goes unconditionally to a diagonal-major
// LDS buffer: slot (d,v) is only ever read for t=d-v in [0,63], so inactive
// lanes' garbage lands in never-read slots -> zero guards in the loop.
__global__ void __launch_bounds__(256) dp_kernel(
    const float* __restrict__ g, float* __restrict__ out)
{
    __shared__ float sc[3 * T * V];        // [kind][t][v], log2-domain
    __shared__ float sAd[127 * V + V];     // diag-major alpha

    const int b = blockIdx.x, tid = threadIdx.x;

    {   // stage 48 KB: 12 float4 per thread, one contiguous stream
        const float4* __restrict__ src = (const float4*)(g + (size_t)b * 3 * T * V);
        float4* dst = (float4*)sc;
        #pragma unroll
        for (int j = 0; j < 12; ++j) dst[tid + j * 256] = src[tid + j * 256];
    }
    if (tid == 0) sAd[0] = 0.0f;           // alpha[0][0]
    __syncthreads();

    if (tid < 64) {
        const int v = tid;
        const int negi = __float_as_int(NEG);
        float a1 = (v == 0) ? 0.0f : NEG;  // alpha[t-1 at next step][v]
        float a2 = NEG;

        constexpr int PD = 7;              // prefetch depth; 126 = 17*7 + 7
        float pD[PD], pI[PD], pS[PD];
        #pragma unroll
        for (int k = 0; k < PD; ++k) {
            const int tc = min(max(1 + k - v, 0), T - 1);
            const int off = tc * V + v;
            pD[k] = sc[off]; pI[k] = sc[T*V + off]; pS[k] = sc[2*T*V + off];
        }

        for (int gq = 0; gq < 17; ++gq) {
            #pragma unroll
            for (int k = 0; k < PD; ++k) {
                const int d = gq * PD + 1 + k;
                const float lf1 = shr1(a1, negi);   // alpha[t,   v-1]
                const float lf2 = shr1(a2, negi);   // alpha[t-1, v-1]
                const float xd = pD[k] + a1;
                const float xs = pS[k] + lf2;
                const float xi = pI[k] + lf1;
                {   // prefetch step d+PD (result needed ~350 cy later)
                    const int tc = min(max(d + PD - v, 0), T - 1);
                    const int off = tc * V + v;
                    pD[k] = sc[off]; pI[k] = sc[T*V + off]; pS[k] = sc[2*T*V + off];
                }
                const float m = fmaxf(fmaxf(xd, xs), xi);     // v_max3_f32
                const float s = fexp2(xd - m) + fexp2(xs - m) + fexp2(xi - m);
                const float a = m + flog2(s);
                sAd[d * V + v] = a;                  // unconditional, off-chain
                a2 = a1; a1 = a;
            }
        }
        #pragma unroll
        for (int k = 0; k < PD; ++k) {               // epilogue d = 120..126
            const int d = 120 + k;
            const float lf1 = shr1(a1, negi);
            const float lf2 = shr1(a2, negi);
            const float xd = pD[k] + a1;
            const float xs = pS[k] + lf2;
            const float xi = pI[k] + lf1;
            const float m = fmaxf(fmaxf(xd, xs), xi);
            const float s = fexp2(xd - m) + fexp2(xs - m) + fexp2(xi - m);
            const float a = m + flog2(s);
            sAd[d * V + v] = a;
            a2 = a1; a1 = a;
        }
    }
    __syncthreads();

    {   // writeout: out[t][v] = sAd[(t+v)*64 + v] * ln2, float4-coalesced
        #pragma unroll
        for (int j = 0; j < 4; ++j) {
            const int idx = tid + j * 256;           // f4 tile 0..1023
            const int t = idx >> 4, v4 = (idx & 15) * 4;
            float4 r;
            r.x = sAd[(t + v4 + 0) * V + v4 + 0] * LN2;
            r.y = sAd[(t + v4 + 1) * V + v4 + 1] * LN2;
            r.z = sAd[(t + v4 + 2) * V + v4 + 2] * LN2;
            r.w = sAd[(t + v4 + 3) * V + v4 + 3] * LN2;
            ((float4*)out)[(size_t)b * 1024 + idx] = r;
        }
    }
}

extern "C" void kernel_launch(void* const* d_in, const int* in_sizes, int n_in,
                              void* d_out, int out_size, void* d_ws, size_t ws_size,
                              hipStream_t stream) {
    const float* as      = (const float*)d_in[0];
    const int*   del_ids = (const int*)d_in[1];
    const int*   ins_ids = (const int*)d_in[2];
    const int*   sub_ids = (const int*)d_in[3];
    float*       out     = (float*)d_out;
    float*       g       = (float*)d_ws;   // [B][3][T*V] = 3 MiB

    gather_kernel<<<B * T, 192, 0, stream>>>(as, del_ids, ins_ids, sub_ids, g);
    dp_kernel<<<B, 256, 0, stream>>>(g, out);
}